// Round 16
// baseline (121.044 us; speedup 1.0000x reference)
//
#include <hip/hip_runtime.h>
#include <hip/hip_bf16.h>

#define B_ 8
#define H_ 8
#define S_ 1024
#define D_ 64
#define KT 32            // k cols per tile
#define NSTEP 16         // tiles per KV half (512/32)

typedef float f32x16 __attribute__((ext_vector_type(16)));
typedef short s16x8 __attribute__((ext_vector_type(8)));
typedef unsigned int u32;

// (1/sqrt(2*D)) * log2(e): softmax done base-2; folded into Q at load time
#define CSCALE ((float)(1.4426950408889634 / 11.313708498984761))

static __device__ __forceinline__ unsigned short f2bf(float f) {
    union { float f; unsigned u; } v; v.f = f;
    unsigned r = v.u + 0x7FFF + ((v.u >> 16) & 1);   // RNE
    return (unsigned short)(r >> 16);
}

static __device__ __forceinline__ u32 cvtpk(float lo, float hi) {
    u32 r;
    asm("v_cvt_pk_bf16_f32 %0, %1, %2" : "=v"(r) : "v"(lo), "v"(hi));
    return r;
}

// async global->LDS, 16B per lane; lds dest = uniform base + lane*16
static __device__ __forceinline__ void glds16(const void* g, void* l) {
    __builtin_amdgcn_global_load_lds(
        (const __attribute__((address_space(1))) unsigned int*)(uintptr_t)g,
        (__attribute__((address_space(3))) unsigned int*)(unsigned)(uintptr_t)l,
        16, 0, 0);
}

// ---------------- pairs kernel (+fused V transpose) ----------------
// Part A: replicate reference IoU-argmax bit-exactly (32-way j-split).
// Part B (independent of pairs): transpose one (bh, stile) V tile into
// fragment-linear bf16 layout Vt[bh]: 32 tiles x (4 frags L=dt*2+ks x 64 lanes x 8):
//   V[kt*32 + ks*16 + (lane>>5)*8 + e][dt*32 + (lane&31)].
__global__ __launch_bounds__(256) void pairs_kernel(const float* __restrict__ centers,
                                                    const float* __restrict__ v,
                                                    int* __restrict__ p0,
                                                    int* __restrict__ p1,
                                                    unsigned short* __restrict__ Vt) {
#pragma clang fp contract(off)
    __shared__ __align__(16) float4 box4[S_];
    __shared__ float areas[S_], l1s[S_];
    __shared__ float tile[64][65];
    const int b = blockIdx.y;
    const int t = threadIdx.x;
    for (int idx = t; idx < S_; idx += 256) {
        const float4 c = *reinterpret_cast<const float4*>(centers + ((size_t)b * S_ + idx) * 4);
        const float cx = c.x, cy = c.y, hh = c.z, ww = c.w;  // order: cx, cy, h, w
        const float x0 = cx - 0.5f * ww;
        const float y0 = cy - 0.5f * hh;
        const float x1 = cx + 0.5f * ww;
        const float y1 = cy + 0.5f * hh;
        box4[idx] = float4{x0, y0, x1, y1};
        areas[idx] = (x1 - x0) * (y1 - y0);
        l1s[idx] = fabsf(x1 - x0) + fabsf(y1 - y0);
    }
    __syncthreads();
    {
        const int i = blockIdx.x * 8 + (t >> 5);
        const int c32 = t & 31;
        const float4 bi = box4[i];
        const float ai = areas[i];
        float best = -1e38f; int arg = 0;
        // j = it*32 + c32: consecutive lanes -> consecutive j; ascending within thread
        #pragma unroll 4
        for (int it = 0; it < 32; ++it) {
            const int j = it * 32 + c32;
            const float4 bj = box4[j];
            const float aj = areas[j];
            // NOTE: replicates reference exactly, including maximum() used for BOTH mins and maxs
            float wx = fmaxf(bi.z, bj.z) - fmaxf(bi.x, bj.x);
            float wy = fmaxf(bi.w, bj.w) - fmaxf(bi.y, bj.y);
            wx = fmaxf(wx, 0.0f);
            wy = fmaxf(wy, 0.0f);
            const float inter = wx * wy;
            const float uni = (ai + aj) - inter;
            float val = inter / uni;
            if (j == i) val = val - 1.0f;   // -eye AFTER the division, as in reference
            if (val > best) { best = val; arg = j; }   // keeps smallest j at max within thread
        }
        // merge 32 chunks: smaller j wins ties (first-occurrence argmax)
        #pragma unroll
        for (int m = 1; m <= 16; m <<= 1) {
            const float ob = __shfl_xor(best, m);
            const int oa = __shfl_xor(arg, m);
            if (ob > best || (ob == best && oa < arg)) { best = ob; arg = oa; }
        }
        if (c32 == 0) {
            const int partner = arg;
            const float l1i = l1s[i], l1p = l1s[partner];
            const int keep = (l1i >= l1p) ? 1 : 0;
            p0[b * S_ + i] = keep ? i : partner;
            p1[b * S_ + i] = keep ? partner : i;
        }
    }
    // ---- Part B: V transpose for unit = b*128 + bx -> (bh = unit>>4, stile = unit&15) ----
    {
        const int unit = b * 128 + blockIdx.x;
        const int bh = unit >> 4;
        const int stile = unit & 15;
        const int s0 = stile * 64;
        const int kt0 = stile * 2;
        const float* vp = v + ((size_t)bh * S_ + s0) * D_;
        const int row = t >> 2, cpart = (t & 3) * 16;
        for (int jj = 0; jj < 4; ++jj) {
            const float4 x = *reinterpret_cast<const float4*>(&vp[(size_t)row * D_ + cpart + jj * 4]);
            tile[row][cpart + jj * 4 + 0] = x.x;
            tile[row][cpart + jj * 4 + 1] = x.y;
            tile[row][cpart + jj * 4 + 2] = x.z;
            tile[row][cpart + jj * 4 + 3] = x.w;
        }
        __syncthreads();
        unsigned short* VtB = Vt + (size_t)bh * 65536;
        for (int it = 0; it < 2; ++it) {
            const int flat = it * 256 + t;      // 0..511
            const int ktl = flat >> 8;          // 0..1
            const int L = (flat >> 6) & 3;
            const int lane = flat & 63;
            const int dt = L >> 1, ks = L & 1;
            const int d = dt * 32 + (lane & 31);
            const int sr = ktl * 32 + ks * 16 + ((lane >> 5) << 3);
            unsigned short hh[8];
            #pragma unroll
            for (int e = 0; e < 8; ++e) hh[e] = f2bf(tile[sr + e][d]);
            *reinterpret_cast<s16x8*>(VtB + ((size_t)((kt0 + ktl) * 4 + L) * 64 + lane) * 8) =
                *reinterpret_cast<s16x8*>(hh);
        }
    }
}

// ---------------- prep: gathered K' bf16, FRAGMENT-LINEAR, KT=32 ----------------
// Kg[bh]: 32 tiles x (8 frags L x 64 lanes x 8 bf16).  Frag L: K'[kt*32+(lane&31)]
//   chunk c = 2L + (lane>>5)  (chunk = 8 consecutive elems of the 128-wide K' row).
__global__ __launch_bounds__(256) void prep_k(const float* __restrict__ k,
                                              const int* __restrict__ p0,
                                              const int* __restrict__ p1,
                                              unsigned short* __restrict__ Kg) {
    const int gid = blockIdx.x;                 // XCD-swizzled 1D grid: 1024 blocks
    const int grp = (gid >> 3) & 15;            // 64-row group (2 ktiles)
    const int bh = ((gid >> 7) << 3) | (gid & 7);
    const int b = bh >> 3;
    const int s0 = grp * 64;
    const int kt0 = grp * 2;
    const int t = threadIdx.x;
    const float* kp = k + (size_t)bh * S_ * D_;
    const int* p0b = p0 + b * S_;
    const int* p1b = p1 + b * S_;
    unsigned short* KgB = Kg + (size_t)bh * 131072;
    for (int it = 0; it < 4; ++it) {
        const int flat = it * 256 + t;      // 0..1023
        const int ktl = flat >> 9;          // 0..1
        const int L = (flat >> 6) & 7;
        const int lane = flat & 63;
        const int s = s0 + ktl * 32 + (lane & 31);
        const int c = (L << 1) + (lane >> 5);
        const int i0 = p0b[s], i1 = p1b[s];
        const float* src = (c < 8) ? (kp + (size_t)i0 * D_ + c * 8)
                                   : (kp + (size_t)i1 * D_ + (c - 8) * 8);
        const float4 f0 = *reinterpret_cast<const float4*>(src);
        const float4 f1 = *reinterpret_cast<const float4*>(src + 4);
        union { u32 u[4]; s16x8 v; } pk;
        pk.u[0] = cvtpk(f0.x, f0.y);
        pk.u[1] = cvtpk(f0.z, f0.w);
        pk.u[2] = cvtpk(f1.x, f1.y);
        pk.u[3] = cvtpk(f1.z, f1.w);
        *reinterpret_cast<s16x8*>(KgB + ((size_t)((kt0 + ktl) * 8 + L) * 64 + lane) * 8) = pk.v;
    }
}

// ---------------- fused flash attention: r15 + V register-prefetch (no V in LDS) ----------------
// In-block KV-split-2, 32KB K-dbuf LDS, 4 blocks/CU.  K double-buffered (barrier
// handoff); V fragments prefetched global->VGPR ONE TILE AHEAD (vfa/vfb rotation,
// unroll-by-2, compiler-tracked register dependency); no-max softmax; permlane exchange.
__global__ __launch_bounds__(256, 4) void attn_kernel(const float* __restrict__ q,
                                                      const unsigned short* __restrict__ Kg,
                                                      const unsigned short* __restrict__ Vt,
                                                      const int* __restrict__ p0,
                                                      const int* __restrict__ p1,
                                                      float* __restrict__ out) {
    __shared__ __align__(16) char smem[34304];   // 2 streams x K dbuf 16KB; overlaid by combine
    auto Osh = reinterpret_cast<float(*)[32][66]>(smem);        // [4][32][66] = 33792B
    auto lsh = reinterpret_cast<float(*)[32]>(smem + 33792);    // [4][32] = 512B

    const int tid = threadIdx.x;
    const int w = tid >> 6;          // wave 0..3
    const int r = w >> 1;            // row half
    const int s = w & 1;             // KV half
    const int lane = tid & 63;
    const int qc = lane & 31;        // q-row within wave tile / kcol within K-tile
    const int hi = lane >> 5;
    const int gid = blockIdx.x;      // XCD-swizzled 1D grid: 1024 blocks
    const int rowtile = (gid >> 3) & 15;
    const int bh = ((gid >> 7) << 3) | (gid & 7);
    const int b = bh >> 3;
    const int h = bh & 7;

    const float* qp = q + (size_t)bh * S_ * D_;
    const unsigned short* KgB = Kg + (size_t)bh * 131072;
    const unsigned short* VtL = Vt + (size_t)bh * 65536 + (size_t)lane * 8;  // per-lane base

    char* const strbase = smem + s * 16384;      // this stream's K bufs at +0 / +8192

    // K staging: each wave stages 4 of the 8 K frags of its stream (split by r)
    auto STAGE_K = [&](int t, int buf) {
        const int kt = s * NSTEP + t;
        char* base = strbase + buf * 8192;
        #pragma unroll
        for (int j = 0; j < 4; ++j) {
            const int L = r * 4 + j;
            glds16(KgB + ((size_t)(kt * 8 + L) * 64 + lane) * 8, base + L * 1024);
        }
    };
    // V fragments: direct global->VGPR (fragment-linear, coalesced 1KB per load)
    auto LOADV = [&](s16x8* vf, int t) {
        const int kt = s * NSTEP + t;
        #pragma unroll
        for (int L = 0; L < 4; ++L)
            vf[L] = *reinterpret_cast<const s16x8*>(VtL + (size_t)(kt * 4 + L) * 512);
    };

    s16x8 vfa[4], vfb[4];
    LOADV(vfa, 0);
    STAGE_K(0, 0);

    // ---- gather this lane's Q' row slices into B-fragments (pre-scaled by CSCALE) ----
    s16x8 qf[8];
    {
        const int qr = rowtile * 64 + r * 32 + qc;
        const int i0 = p0[b * S_ + qr], i1 = p1[b * S_ + qr];
        #pragma unroll
        for (int p = 0; p < 8; ++p) {
            const int k0 = 16 * p + 8 * hi;
            const float* src = (p < 4) ? (qp + (size_t)i0 * D_ + k0)
                                       : (qp + (size_t)i1 * D_ + (k0 - 64));
            const float4 f0 = *reinterpret_cast<const float4*>(src);
            const float4 f1 = *reinterpret_cast<const float4*>(src + 4);
            union { u32 u[4]; s16x8 v; } pk;
            pk.u[0] = cvtpk(f0.x * CSCALE, f0.y * CSCALE);
            pk.u[1] = cvtpk(f0.z * CSCALE, f0.w * CSCALE);
            pk.u[2] = cvtpk(f1.x * CSCALE, f1.y * CSCALE);
            pk.u[3] = cvtpk(f1.z * CSCALE, f1.w * CSCALE);
            qf[p] = pk.v;
        }
    }
    __syncthreads();   // K[0] landed (implicit vmcnt drain); vfa also resident

    f32x16 oacc0 = {}, oacc1 = {};   // O^T accumulators: d-tiles 0/1 x qrow=qc (unnormalized)
    f32x16 lsum = {};                // per-lane P sums, reduced once at the end

    // one tile of compute against K buf `buf` and register V `vf`
    auto COMPUTE = [&](int buf, const s16x8* vf) {
        const unsigned short* KsT = reinterpret_cast<const unsigned short*>(strbase + buf * 8192);
        // ---- swapped QK^T: D[kcol][qrow], 32 kcols x kdim 128 = 8 MFMAs ----
        f32x16 st = {};
        #pragma unroll
        for (int L = 0; L < 8; ++L) {
            const s16x8 kf = *reinterpret_cast<const s16x8*>(KsT + L * 512 + lane * 8);
            st = __builtin_amdgcn_mfma_f32_32x32x16_bf16(kf, qf[L], st, 0, 0, 0);
        }
        // ---- no-max softmax: P = exp2(score); accumulate l as a vector ----
        #pragma unroll
        for (int i = 0; i < 16; ++i) st[i] = exp2f(st[i]);
        lsum += st;
        // ---- pack P to bf16 pairs (in-register) ----
        u32 U[8];
        #pragma unroll
        for (int i = 0; i < 8; ++i) U[i] = cvtpk(st[2 * i], st[2 * i + 1]);
        // ---- PV: cross-half exchange via v_permlane32_swap (VALU, no DS) ----
        #pragma unroll
        for (int ks = 0; ks < 2; ++ks) {
            const int a = 4 * ks;
            u32 w0 = U[a], w2 = U[a + 2];
            u32 w1 = U[a + 1], w3 = U[a + 3];
            asm("v_permlane32_swap_b32 %0, %1" : "+v"(w0), "+v"(w2));
            asm("v_permlane32_swap_b32 %0, %1" : "+v"(w1), "+v"(w3));
            union { u32 u[4]; s16x8 v; } pf;
            pf.u[0] = w0; pf.u[1] = w1; pf.u[2] = w2; pf.u[3] = w3;
            oacc0 = __builtin_amdgcn_mfma_f32_32x32x16_bf16(vf[ks], pf.v, oacc0, 0, 0, 0);
            oacc1 = __builtin_amdgcn_mfma_f32_32x32x16_bf16(vf[2 + ks], pf.v, oacc1, 0, 0, 0);
        }
    };

    // main loop unrolled by 2: vfa/vfb rotation with static names (no runtime indexing)
    for (int t = 0; t < NSTEP; t += 2) {
        // ---- even tile t: compute with vfa (K buf 0), prefetch V[t+1]->vfb, K[t+1]->buf1 ----
        LOADV(vfb, t + 1);             // t+1 <= 15 always inside loop
        STAGE_K(t + 1, 1);
        COMPUTE(0, vfa);
        __syncthreads();               // K[t+1] landed; all waves done reading K buf 0
        // ---- odd tile t+1: compute with vfb (K buf 1), prefetch V[t+2]->vfa, K[t+2]->buf0 ----
        if (t + 2 < NSTEP) {
            LOADV(vfa, t + 2);
            STAGE_K(t + 2, 0);
        }
        COMPUTE(1, vfb);
        __syncthreads();               // K[t+2] landed; all waves done reading K buf 1
    }

    // ---- final l reduction: 16-elem tree + one cross-half shfl ----
    float l_run;
    {
        float a8[8];
        #pragma unroll
        for (int i = 0; i < 8; ++i) a8[i] = lsum[i] + lsum[i + 8];
        #pragma unroll
        for (int i = 0; i < 4; ++i) a8[i] += a8[i + 4];
        l_run = (a8[0] + a8[1]) + (a8[2] + a8[3]);
        l_run += __shfl_xor(l_run, 32);
    }

    // ---- write partials (unnormalized O, l) to LDS (overlays staging buffers) ----
    #pragma unroll
    for (int i = 0; i < 16; ++i) {
        const int d0 = (i & 3) + 8 * (i >> 2) + 4 * hi;
        Osh[w][qc][d0] = oacc0[i];
        Osh[w][qc][32 + d0] = oacc1[i];
    }
    if (hi == 0) lsh[w][qc] = l_run;
    __syncthreads();

    // ---- deterministic 2-way combine (over s) per row half; coalesced store ----
    const int row = tid >> 2;          // 0..63
    const int rr = row >> 5;
    const int lrow = row & 31;
    const int dc = (tid & 3) * 16;     // 16 d per thread
    const int wa = rr * 2, wb = rr * 2 + 1;
    const float den = lsh[wa][lrow] + lsh[wb][lrow];
    const float inv = 1.0f / den;
    const int qrg = rowtile * 64 + row;
    float* orow = out + ((size_t)b * S_ + qrg) * (H_ * D_) + h * D_ + dc;
    #pragma unroll
    for (int e4 = 0; e4 < 4; ++e4) {
        float4 o;
        o.x = (Osh[wa][lrow][dc + e4 * 4 + 0] + Osh[wb][lrow][dc + e4 * 4 + 0]) * inv;
        o.y = (Osh[wa][lrow][dc + e4 * 4 + 1] + Osh[wb][lrow][dc + e4 * 4 + 1]) * inv;
        o.z = (Osh[wa][lrow][dc + e4 * 4 + 2] + Osh[wb][lrow][dc + e4 * 4 + 2]) * inv;
        o.w = (Osh[wa][lrow][dc + e4 * 4 + 3] + Osh[wb][lrow][dc + e4 * 4 + 3]) * inv;
        *reinterpret_cast<float4*>(orow + e4 * 4) = o;
    }
}

extern "C" void kernel_launch(void* const* d_in, const int* in_sizes, int n_in,
                              void* d_out, int out_size, void* d_ws, size_t ws_size,
                              hipStream_t stream) {
    (void)in_sizes; (void)n_in; (void)out_size; (void)ws_size;
    const float* q = (const float*)d_in[0];
    const float* k = (const float*)d_in[1];
    const float* v = (const float*)d_in[2];
    const float* c = (const float*)d_in[3];
    float* out = (float*)d_out;
    int* p0 = (int*)d_ws;                                   // [B_, S_] = 32KB
    int* p1 = p0 + B_ * S_;                                 // 32KB
    unsigned short* Kg = (unsigned short*)((char*)d_ws + 65536);        // 16.8MB
    unsigned short* Vt = Kg + (size_t)B_ * H_ * S_ * 128;               // 8.4MB
    pairs_kernel<<<dim3(128, 8), 256, 0, stream>>>(c, v, p0, p1, Vt);
    prep_k<<<dim3(1024), 256, 0, stream>>>(k, p0, p1, Kg);
    attn_kernel<<<dim3(1024), 256, 0, stream>>>(q, Kg, Vt, p0, p1, out);
}

// Round 17
// 70.619 us; speedup vs baseline: 1.7140x; 1.7140x over previous
//
#include <hip/hip_runtime.h>
#include <hip/hip_bf16.h>

#define B_ 8
#define H_ 8
#define S_ 1024
#define D_ 64
#define KT 32            // k cols per tile
#define NSTEP 16         // tiles per KV half (512/32)

typedef float f32x16 __attribute__((ext_vector_type(16)));
typedef short s16x8 __attribute__((ext_vector_type(8)));
typedef unsigned int u32;

// (1/sqrt(2*D)) * log2(e): softmax done base-2; folded into Q at load time
#define CSCALE ((float)(1.4426950408889634 / 11.313708498984761))

static __device__ __forceinline__ unsigned short f2bf(float f) {
    union { float f; unsigned u; } v; v.f = f;
    unsigned r = v.u + 0x7FFF + ((v.u >> 16) & 1);   // RNE
    return (unsigned short)(r >> 16);
}

static __device__ __forceinline__ u32 cvtpk(float lo, float hi) {
    u32 r;
    asm("v_cvt_pk_bf16_f32 %0, %1, %2" : "=v"(r) : "v"(lo), "v"(hi));
    return r;
}

// async global->LDS, 16B per lane; lds dest = uniform base + lane*16
static __device__ __forceinline__ void glds16(const void* g, void* l) {
    __builtin_amdgcn_global_load_lds(
        (const __attribute__((address_space(1))) unsigned int*)(uintptr_t)g,
        (__attribute__((address_space(3))) unsigned int*)(unsigned)(uintptr_t)l,
        16, 0, 0);
}

// ---------------- pairs kernel (+fused V transpose) ----------------
// Part A: replicate reference IoU-argmax bit-exactly (32-way j-split).
// Part B (independent of pairs): transpose one (bh, stile) V tile into
// fragment-linear bf16 layout Vt[bh]: 32 tiles x (4 frags L=dt*2+ks x 64 lanes x 8):
//   V[kt*32 + ks*16 + (lane>>5)*8 + e][dt*32 + (lane&31)].
__global__ __launch_bounds__(256) void pairs_kernel(const float* __restrict__ centers,
                                                    const float* __restrict__ v,
                                                    int* __restrict__ p0,
                                                    int* __restrict__ p1,
                                                    unsigned short* __restrict__ Vt) {
#pragma clang fp contract(off)
    __shared__ __align__(16) float4 box4[S_];
    __shared__ float areas[S_], l1s[S_];
    __shared__ float tile[64][65];
    const int b = blockIdx.y;
    const int t = threadIdx.x;
    for (int idx = t; idx < S_; idx += 256) {
        const float4 c = *reinterpret_cast<const float4*>(centers + ((size_t)b * S_ + idx) * 4);
        const float cx = c.x, cy = c.y, hh = c.z, ww = c.w;  // order: cx, cy, h, w
        const float x0 = cx - 0.5f * ww;
        const float y0 = cy - 0.5f * hh;
        const float x1 = cx + 0.5f * ww;
        const float y1 = cy + 0.5f * hh;
        box4[idx] = float4{x0, y0, x1, y1};
        areas[idx] = (x1 - x0) * (y1 - y0);
        l1s[idx] = fabsf(x1 - x0) + fabsf(y1 - y0);
    }
    __syncthreads();
    {
        const int i = blockIdx.x * 8 + (t >> 5);
        const int c32 = t & 31;
        const float4 bi = box4[i];
        const float ai = areas[i];
        float best = -1e38f; int arg = 0;
        // j = it*32 + c32: consecutive lanes -> consecutive j; ascending within thread
        #pragma unroll 4
        for (int it = 0; it < 32; ++it) {
            const int j = it * 32 + c32;
            const float4 bj = box4[j];
            const float aj = areas[j];
            // NOTE: replicates reference exactly, including maximum() used for BOTH mins and maxs
            float wx = fmaxf(bi.z, bj.z) - fmaxf(bi.x, bj.x);
            float wy = fmaxf(bi.w, bj.w) - fmaxf(bi.y, bj.y);
            wx = fmaxf(wx, 0.0f);
            wy = fmaxf(wy, 0.0f);
            const float inter = wx * wy;
            const float uni = (ai + aj) - inter;
            float val = inter / uni;
            if (j == i) val = val - 1.0f;   // -eye AFTER the division, as in reference
            if (val > best) { best = val; arg = j; }   // keeps smallest j at max within thread
        }
        // merge 32 chunks: smaller j wins ties (first-occurrence argmax)
        #pragma unroll
        for (int m = 1; m <= 16; m <<= 1) {
            const float ob = __shfl_xor(best, m);
            const int oa = __shfl_xor(arg, m);
            if (ob > best || (ob == best && oa < arg)) { best = ob; arg = oa; }
        }
        if (c32 == 0) {
            const int partner = arg;
            const float l1i = l1s[i], l1p = l1s[partner];
            const int keep = (l1i >= l1p) ? 1 : 0;
            p0[b * S_ + i] = keep ? i : partner;
            p1[b * S_ + i] = keep ? partner : i;
        }
    }
    // ---- Part B: V transpose for unit = b*128 + bx -> (bh = unit>>4, stile = unit&15) ----
    {
        const int unit = b * 128 + blockIdx.x;
        const int bh = unit >> 4;
        const int stile = unit & 15;
        const int s0 = stile * 64;
        const int kt0 = stile * 2;
        const float* vp = v + ((size_t)bh * S_ + s0) * D_;
        const int row = t >> 2, cpart = (t & 3) * 16;
        for (int jj = 0; jj < 4; ++jj) {
            const float4 x = *reinterpret_cast<const float4*>(&vp[(size_t)row * D_ + cpart + jj * 4]);
            tile[row][cpart + jj * 4 + 0] = x.x;
            tile[row][cpart + jj * 4 + 1] = x.y;
            tile[row][cpart + jj * 4 + 2] = x.z;
            tile[row][cpart + jj * 4 + 3] = x.w;
        }
        __syncthreads();
        unsigned short* VtB = Vt + (size_t)bh * 65536;
        for (int it = 0; it < 2; ++it) {
            const int flat = it * 256 + t;      // 0..511
            const int ktl = flat >> 8;          // 0..1
            const int L = (flat >> 6) & 3;
            const int lane = flat & 63;
            const int dt = L >> 1, ks = L & 1;
            const int d = dt * 32 + (lane & 31);
            const int sr = ktl * 32 + ks * 16 + ((lane >> 5) << 3);
            unsigned short hh[8];
            #pragma unroll
            for (int e = 0; e < 8; ++e) hh[e] = f2bf(tile[sr + e][d]);
            *reinterpret_cast<s16x8*>(VtB + ((size_t)((kt0 + ktl) * 4 + L) * 64 + lane) * 8) =
                *reinterpret_cast<s16x8*>(hh);
        }
    }
}

// ---------------- prep: gathered K' bf16, FRAGMENT-LINEAR, KT=32 ----------------
// Kg[bh]: 32 tiles x (8 frags L x 64 lanes x 8 bf16).  Frag L: K'[kt*32+(lane&31)]
//   chunk c = 2L + (lane>>5)  (chunk = 8 consecutive elems of the 128-wide K' row).
__global__ __launch_bounds__(256) void prep_k(const float* __restrict__ k,
                                              const int* __restrict__ p0,
                                              const int* __restrict__ p1,
                                              unsigned short* __restrict__ Kg) {
    const int gid = blockIdx.x;                 // XCD-swizzled 1D grid: 1024 blocks
    const int grp = (gid >> 3) & 15;            // 64-row group (2 ktiles)
    const int bh = ((gid >> 7) << 3) | (gid & 7);
    const int b = bh >> 3;
    const int s0 = grp * 64;
    const int kt0 = grp * 2;
    const int t = threadIdx.x;
    const float* kp = k + (size_t)bh * S_ * D_;
    const int* p0b = p0 + b * S_;
    const int* p1b = p1 + b * S_;
    unsigned short* KgB = Kg + (size_t)bh * 131072;
    for (int it = 0; it < 4; ++it) {
        const int flat = it * 256 + t;      // 0..1023
        const int ktl = flat >> 9;          // 0..1
        const int L = (flat >> 6) & 7;
        const int lane = flat & 63;
        const int s = s0 + ktl * 32 + (lane & 31);
        const int c = (L << 1) + (lane >> 5);
        const int i0 = p0b[s], i1 = p1b[s];
        const float* src = (c < 8) ? (kp + (size_t)i0 * D_ + c * 8)
                                   : (kp + (size_t)i1 * D_ + (c - 8) * 8);
        const float4 f0 = *reinterpret_cast<const float4*>(src);
        const float4 f1 = *reinterpret_cast<const float4*>(src + 4);
        union { u32 u[4]; s16x8 v; } pk;
        pk.u[0] = cvtpk(f0.x, f0.y);
        pk.u[1] = cvtpk(f0.z, f0.w);
        pk.u[2] = cvtpk(f1.x, f1.y);
        pk.u[3] = cvtpk(f1.z, f1.w);
        *reinterpret_cast<s16x8*>(KgB + ((size_t)((kt0 + ktl) * 8 + L) * 64 + lane) * 8) = pk.v;
    }
}

// ---------------- fused flash attention: r14 structure + permlane32_swap P-exchange ----------------
// In-block KV-split-2, 40KB LDS, 4 blocks/CU.  K double-buffered (barrier handoff);
// V single-buffered with per-wave counted-vmcnt handoff (duplicate stage, benign);
// no-max softmax; single 8-chain QK^T; PV exchange via v_permlane32_swap (VALU, no DS).
__global__ __launch_bounds__(256, 4) void attn_kernel(const float* __restrict__ q,
                                                      const unsigned short* __restrict__ Kg,
                                                      const unsigned short* __restrict__ Vt,
                                                      const int* __restrict__ p0,
                                                      const int* __restrict__ p1,
                                                      float* __restrict__ out) {
    __shared__ __align__(16) char smem[40960];   // 2 streams x (K dbuf 16KB + V 4KB); overlaid by combine
    auto Osh = reinterpret_cast<float(*)[32][66]>(smem);        // [4][32][66] = 33792B
    auto lsh = reinterpret_cast<float(*)[32]>(smem + 33792);    // [4][32]

    const int tid = threadIdx.x;
    const int w = tid >> 6;          // wave 0..3
    const int r = w >> 1;            // row half
    const int s = w & 1;             // KV half
    const int lane = tid & 63;
    const int qc = lane & 31;        // q-row within wave tile / kcol within K-tile
    const int hi = lane >> 5;
    const int gid = blockIdx.x;      // XCD-swizzled 1D grid: 1024 blocks
    const int rowtile = (gid >> 3) & 15;
    const int bh = ((gid >> 7) << 3) | (gid & 7);
    const int b = bh >> 3;
    const int h = bh & 7;

    const float* qp = q + (size_t)bh * S_ * D_;
    const unsigned short* KgB = Kg + (size_t)bh * 131072;
    const unsigned short* VtB = Vt + (size_t)bh * 65536;

    char* const strbase = smem + s * 20480;      // this stream: K bufs at +0/+8192, V at +16384

    // K staging: each wave stages 4 of the 8 K frags of its stream (split by r)
    auto STAGE_K = [&](int t, int buf) {
        const int kt = s * NSTEP + t;
        char* base = strbase + buf * 8192;
        #pragma unroll
        for (int j = 0; j < 4; ++j) {
            const int L = r * 4 + j;
            glds16(KgB + ((size_t)(kt * 8 + L) * 64 + lane) * 8, base + L * 1024);
        }
    };
    // V staging: BOTH waves of the stream stage the full V tile (identical bytes)
    auto STAGE_V = [&](int t) {
        const int kt = s * NSTEP + t;
        #pragma unroll
        for (int L = 0; L < 4; ++L)
            glds16(VtB + ((size_t)(kt * 4 + L) * 64 + lane) * 8, strbase + 16384 + L * 1024);
    };

    STAGE_K(0, 0);

    // ---- gather this lane's Q' row slices into B-fragments (pre-scaled by CSCALE) ----
    s16x8 qf[8];
    {
        const int qr = rowtile * 64 + r * 32 + qc;
        const int i0 = p0[b * S_ + qr], i1 = p1[b * S_ + qr];
        #pragma unroll
        for (int p = 0; p < 8; ++p) {
            const int k0 = 16 * p + 8 * hi;
            const float* src = (p < 4) ? (qp + (size_t)i0 * D_ + k0)
                                       : (qp + (size_t)i1 * D_ + (k0 - 64));
            const float4 f0 = *reinterpret_cast<const float4*>(src);
            const float4 f1 = *reinterpret_cast<const float4*>(src + 4);
            union { u32 u[4]; s16x8 v; } pk;
            pk.u[0] = cvtpk(f0.x * CSCALE, f0.y * CSCALE);
            pk.u[1] = cvtpk(f0.z * CSCALE, f0.w * CSCALE);
            pk.u[2] = cvtpk(f1.x * CSCALE, f1.y * CSCALE);
            pk.u[3] = cvtpk(f1.z * CSCALE, f1.w * CSCALE);
            qf[p] = pk.v;
        }
    }
    __syncthreads();   // K[0] landed (each wave's implicit vmcnt drain covers its 4 frags)

    f32x16 oacc0 = {}, oacc1 = {};   // O^T accumulators: d-tiles 0/1 x qrow=qc (unnormalized)
    f32x16 lsum = {};                // per-lane P sums, reduced once at the end

    for (int t = 0; t < NSTEP; ++t) {
        const int buf = t & 1;
        STAGE_V(t);                                 // 4 oldest outstanding loads = this V
        if (t + 1 < NSTEP) STAGE_K(t + 1, buf ^ 1); // 4 younger loads, land by next barrier

        const unsigned short* KsT = reinterpret_cast<const unsigned short*>(strbase + buf * 8192);
        const unsigned short* VsT = reinterpret_cast<const unsigned short*>(strbase + 16384);

        // ---- swapped QK^T: D[kcol][qrow], 32 kcols x kdim 128 = 8 MFMAs ----
        f32x16 st = {};
        #pragma unroll
        for (int L = 0; L < 8; ++L) {
            const s16x8 kf = *reinterpret_cast<const s16x8*>(KsT + L * 512 + lane * 8);
            st = __builtin_amdgcn_mfma_f32_32x32x16_bf16(kf, qf[L], st, 0, 0, 0);
        }

        // ---- no-max softmax: P = exp2(score); accumulate l as a vector ----
        #pragma unroll
        for (int i = 0; i < 16; ++i) st[i] = exp2f(st[i]);
        lsum += st;

        // ---- pack P to bf16 pairs (in-register) ----
        u32 U[8];
        #pragma unroll
        for (int i = 0; i < 8; ++i) U[i] = cvtpk(st[2 * i], st[2 * i + 1]);

        // ---- wait own V copy (4 oldest of this wave's 8 outstanding), then PV ----
        if (t + 1 < NSTEP) asm volatile("s_waitcnt vmcnt(4)" ::: "memory");
        else               asm volatile("s_waitcnt vmcnt(0)" ::: "memory");
        __builtin_amdgcn_sched_barrier(0);

        // ---- PV: cross-half exchange via v_permlane32_swap (VALU, no DS) ----
        #pragma unroll
        for (int ks = 0; ks < 2; ++ks) {
            const int a = 4 * ks;
            u32 w0 = U[a], w2 = U[a + 2];
            u32 w1 = U[a + 1], w3 = U[a + 3];
            // same lane mapping as the shfl-based exchange (HW-validated r12/r13)
            asm("v_permlane32_swap_b32 %0, %1" : "+v"(w0), "+v"(w2));
            asm("v_permlane32_swap_b32 %0, %1" : "+v"(w1), "+v"(w3));
            union { u32 u[4]; s16x8 v; } pf;
            pf.u[0] = w0; pf.u[1] = w1; pf.u[2] = w2; pf.u[3] = w3;
            const s16x8 vf0 = *reinterpret_cast<const s16x8*>(VsT + ks * 512 + lane * 8);
            oacc0 = __builtin_amdgcn_mfma_f32_32x32x16_bf16(vf0, pf.v, oacc0, 0, 0, 0);
            const s16x8 vf1 = *reinterpret_cast<const s16x8*>(VsT + (2 + ks) * 512 + lane * 8);
            oacc1 = __builtin_amdgcn_mfma_f32_32x32x16_bf16(vf1, pf.v, oacc1, 0, 0, 0);
        }
        __syncthreads();   // closes tile: K[t+1] landed; all waves done with V[t] and K buf
    }

    // ---- final l reduction: 16-elem tree + one cross-half shfl ----
    float l_run;
    {
        float a8[8];
        #pragma unroll
        for (int i = 0; i < 8; ++i) a8[i] = lsum[i] + lsum[i + 8];
        #pragma unroll
        for (int i = 0; i < 4; ++i) a8[i] += a8[i + 4];
        l_run = (a8[0] + a8[1]) + (a8[2] + a8[3]);
        l_run += __shfl_xor(l_run, 32);
    }

    // ---- write partials (unnormalized O, l) to LDS (overlays staging buffers) ----
    #pragma unroll
    for (int i = 0; i < 16; ++i) {
        const int d0 = (i & 3) + 8 * (i >> 2) + 4 * hi;
        Osh[w][qc][d0] = oacc0[i];
        Osh[w][qc][32 + d0] = oacc1[i];
    }
    if (hi == 0) lsh[w][qc] = l_run;
    __syncthreads();

    // ---- deterministic 2-way combine (over s) per row half; coalesced store ----
    const int row = tid >> 2;          // 0..63
    const int rr = row >> 5;
    const int lrow = row & 31;
    const int dc = (tid & 3) * 16;     // 16 d per thread
    const int wa = rr * 2, wb = rr * 2 + 1;
    const float den = lsh[wa][lrow] + lsh[wb][lrow];
    const float inv = 1.0f / den;
    const int qrg = rowtile * 64 + row;
    float* orow = out + ((size_t)b * S_ + qrg) * (H_ * D_) + h * D_ + dc;
    #pragma unroll
    for (int e4 = 0; e4 < 4; ++e4) {
        float4 o;
        o.x = (Osh[wa][lrow][dc + e4 * 4 + 0] + Osh[wb][lrow][dc + e4 * 4 + 0]) * inv;
        o.y = (Osh[wa][lrow][dc + e4 * 4 + 1] + Osh[wb][lrow][dc + e4 * 4 + 1]) * inv;
        o.z = (Osh[wa][lrow][dc + e4 * 4 + 2] + Osh[wb][lrow][dc + e4 * 4 + 2]) * inv;
        o.w = (Osh[wa][lrow][dc + e4 * 4 + 3] + Osh[wb][lrow][dc + e4 * 4 + 3]) * inv;
        *reinterpret_cast<float4*>(orow + e4 * 4) = o;
    }
}

extern "C" void kernel_launch(void* const* d_in, const int* in_sizes, int n_in,
                              void* d_out, int out_size, void* d_ws, size_t ws_size,
                              hipStream_t stream) {
    (void)in_sizes; (void)n_in; (void)out_size; (void)ws_size;
    const float* q = (const float*)d_in[0];
    const float* k = (const float*)d_in[1];
    const float* v = (const float*)d_in[2];
    const float* c = (const float*)d_in[3];
    float* out = (float*)d_out;
    int* p0 = (int*)d_ws;                                   // [B_, S_] = 32KB
    int* p1 = p0 + B_ * S_;                                 // 32KB
    unsigned short* Kg = (unsigned short*)((char*)d_ws + 65536);        // 16.8MB
    unsigned short* Vt = Kg + (size_t)B_ * H_ * S_ * 128;               // 8.4MB
    pairs_kernel<<<dim3(128, 8), 256, 0, stream>>>(c, v, p0, p1, Vt);
    prep_k<<<dim3(1024), 256, 0, stream>>>(k, p0, p1, Kg);
    attn_kernel<<<dim3(1024), 256, 0, stream>>>(q, Kg, Vt, p0, p1, out);
}